// Round 1
// baseline (1036.824 us; speedup 1.0000x reference)
//
#include <hip/hip_runtime.h>
#include <cmath>

namespace {

constexpr int kB = 64;
constexpr int kM = 16384;
constexpr int kW = 128;
constexpr int kH = 8;
constexpr float kEps = 1e-6f;

__device__ __forceinline__ float wave_max(float v) {
  #pragma unroll
  for (int off = 32; off > 0; off >>= 1)
    v = fmaxf(v, __shfl_xor(v, off));
  return v;
}

__device__ __forceinline__ float wave_sum(float v) {
  #pragma unroll
  for (int off = 32; off > 0; off >>= 1)
    v += __shfl_xor(v, off);
  return v;
}

// K1: weighted cosine scores (pre-softmax), written into d_out.
// Grid: kB * (kM/512) blocks of 256 threads; each thread owns 2 memory slots.
__global__ __launch_bounds__(256) void cw_scores(
    const float* __restrict__ mem,
    const float* __restrict__ keys,
    const float* __restrict__ strengths,
    float* __restrict__ out)
{
  __shared__ float s_keys[kH * kW];   // 4 KB, wave-uniform broadcast reads in hot loop
  __shared__ float s_kn[kH];
  __shared__ float s_adj[kH];
  __shared__ float s_part[64];

  const int tid = threadIdx.x;
  const int b = blockIdx.x >> 5;          // 32 chunks of 512 slots per batch
  const int m0 = (blockIdx.x & 31) * 512;

  // Stage keys[b] (1024 floats) into LDS, one float4 per thread, coalesced.
  ((float4*)s_keys)[tid] = ((const float4*)(keys + (size_t)b * (kH * kW)))[tid];
  __syncthreads();

  // Per-block (redundant, cheap) key norms + softplus(strength).
  if (tid < 64) {
    const int h = tid >> 3, p = tid & 7;
    const float* kp = s_keys + h * kW + p * 16;
    float a = 0.f;
    #pragma unroll
    for (int i = 0; i < 16; ++i) a = fmaf(kp[i], kp[i], a);
    s_part[tid] = a;
  }
  __syncthreads();
  if (tid < 8) {
    float s = 0.f;
    #pragma unroll
    for (int i = 0; i < 8; ++i) s += s_part[tid * 8 + i];
    s_kn[tid] = sqrtf(s);
    const float x = strengths[b * kH + tid];
    // softplus(x) = max(x,0) + log1p(exp(-|x|))
    s_adj[tid] = fmaxf(x, 0.f) + log1pf(__expf(-fabsf(x)));
  }
  __syncthreads();

  // Each thread streams two full slots: m0+tid and m0+tid+256.
  const float4* mp0 =
      (const float4*)(mem + ((size_t)b * kM + m0) * kW) + (size_t)tid * (kW / 4);
  const float4* mp1 = mp0 + 256 * (kW / 4);
  const float4* k4 = (const float4*)s_keys;

  float d0[kH], d1[kH];
  float n0 = 0.f, n1 = 0.f;
  #pragma unroll
  for (int h = 0; h < kH; ++h) { d0[h] = 0.f; d1[h] = 0.f; }

  #pragma unroll 4   // 64-B bursts per lane so L1 lines are consumed in-flight
  for (int j = 0; j < kW / 4; ++j) {
    const float4 v0 = mp0[j];
    const float4 v1 = mp1[j];
    n0 = fmaf(v0.x, v0.x, n0); n0 = fmaf(v0.y, v0.y, n0);
    n0 = fmaf(v0.z, v0.z, n0); n0 = fmaf(v0.w, v0.w, n0);
    n1 = fmaf(v1.x, v1.x, n1); n1 = fmaf(v1.y, v1.y, n1);
    n1 = fmaf(v1.z, v1.z, n1); n1 = fmaf(v1.w, v1.w, n1);
    #pragma unroll
    for (int h = 0; h < kH; ++h) {
      const float4 kk = k4[h * (kW / 4) + j];  // wave-uniform -> LDS broadcast
      d0[h] = fmaf(v0.x, kk.x, d0[h]); d0[h] = fmaf(v0.y, kk.y, d0[h]);
      d0[h] = fmaf(v0.z, kk.z, d0[h]); d0[h] = fmaf(v0.w, kk.w, d0[h]);
      d1[h] = fmaf(v1.x, kk.x, d1[h]); d1[h] = fmaf(v1.y, kk.y, d1[h]);
      d1[h] = fmaf(v1.z, kk.z, d1[h]); d1[h] = fmaf(v1.w, kk.w, d1[h]);
    }
  }

  const float mn0 = sqrtf(n0);
  const float mn1 = sqrtf(n1);
  float* op = out + (size_t)b * kH * kM + m0 + tid;
  #pragma unroll
  for (int h = 0; h < kH; ++h) {
    const float w0 = s_adj[h] * d0[h] / fmaf(mn0, s_kn[h], kEps);
    const float w1 = s_adj[h] * d1[h] / fmaf(mn1, s_kn[h], kEps);
    op[h * kM] = w0;          // coalesced dword store per head
    op[h * kM + 256] = w1;
  }
}

// K2: in-place softmax over M per (b,h) row. Grid: kB*kH blocks of 256 threads.
// Whole row (16384 f32) lives in registers: 16 float4 per thread.
__global__ __launch_bounds__(256) void cw_softmax(float* __restrict__ out)
{
  __shared__ float red[16];

  const int tid = threadIdx.x;
  const int wave = tid >> 6, lane = tid & 63;
  float4* p4 = (float4*)(out + (size_t)blockIdx.x * kM);

  float4 vs[16];
  float lmax = -INFINITY;
  #pragma unroll
  for (int k = 0; k < 16; ++k) {
    vs[k] = p4[k * 256 + tid];
    lmax = fmaxf(lmax, fmaxf(fmaxf(vs[k].x, vs[k].y), fmaxf(vs[k].z, vs[k].w)));
  }
  lmax = wave_max(lmax);
  if (lane == 0) red[wave] = lmax;
  __syncthreads();
  const float bmax = fmaxf(fmaxf(red[0], red[1]), fmaxf(red[2], red[3]));

  float lsum = 0.f;
  #pragma unroll
  for (int k = 0; k < 16; ++k) {
    vs[k].x = __expf(vs[k].x - bmax);
    vs[k].y = __expf(vs[k].y - bmax);
    vs[k].z = __expf(vs[k].z - bmax);
    vs[k].w = __expf(vs[k].w - bmax);
    lsum += (vs[k].x + vs[k].y) + (vs[k].z + vs[k].w);
  }
  lsum = wave_sum(lsum);
  if (lane == 0) red[8 + wave] = lsum;
  __syncthreads();
  const float inv = 1.f / ((red[8] + red[9]) + (red[10] + red[11]));

  #pragma unroll
  for (int k = 0; k < 16; ++k) {
    vs[k].x *= inv; vs[k].y *= inv; vs[k].z *= inv; vs[k].w *= inv;
    p4[k * 256 + tid] = vs[k];
  }
}

}  // namespace

extern "C" void kernel_launch(void* const* d_in, const int* in_sizes, int n_in,
                              void* d_out, int out_size, void* d_ws, size_t ws_size,
                              hipStream_t stream) {
  (void)in_sizes; (void)n_in; (void)d_ws; (void)ws_size; (void)out_size;
  const float* mem       = (const float*)d_in[0];
  const float* keys      = (const float*)d_in[1];
  const float* strengths = (const float*)d_in[2];
  float* out = (float*)d_out;

  cw_scores<<<dim3(kB * (kM / 512)), dim3(256), 0, stream>>>(mem, keys, strengths, out);
  cw_softmax<<<dim3(kB * kH), dim3(256), 0, stream>>>(out);
}

// Round 2
// 702.921 us; speedup vs baseline: 1.4750x; 1.4750x over previous
//
#include <hip/hip_runtime.h>
#include <cmath>

namespace {

constexpr int kB = 64;
constexpr int kM = 16384;
constexpr int kW = 128;
constexpr int kH = 8;
constexpr float kEps = 1e-6f;

// ---------------------------------------------------------------------------
// K0: per (b,h) key norm + softplus(strength) into ws.
// ws[0 .. 511]   = ||keys[b,h]||
// ws[512 .. 1023] = softplus(strengths[b,h])
// Grid: kB blocks x 256 threads (8 heads x 32 lanes each).
__global__ __launch_bounds__(256) void cw_stats(
    const float* __restrict__ keys,
    const float* __restrict__ strengths,
    float* __restrict__ ws)
{
  const int b = blockIdx.x;
  const int t = threadIdx.x;
  const int h = t >> 5, p = t & 31;  // 32 lanes per head, xor-shuffles stay inside the group
  const float4 v = ((const float4*)(keys + ((size_t)b * kH + h) * kW))[p];
  float a = v.x * v.x + v.y * v.y + v.z * v.z + v.w * v.w;
  #pragma unroll
  for (int off = 16; off > 0; off >>= 1) a += __shfl_xor(a, off);
  if (p == 0) {
    ws[b * kH + h] = sqrtf(a);
    const float x = strengths[b * kH + h];
    ws[kB * kH + b * kH + h] = fmaxf(x, 0.f) + log1pf(__expf(-fabsf(x)));
  }
}

// ---------------------------------------------------------------------------
// K1: weighted cosine scores (pre-softmax) into d_out.
// Grid: kB * (kM/64) = 16384 blocks x 256 threads. Block = one batch b, 64 slots.
// Fully-coalesced HBM reads -> LDS tile (xor-swizzled float4 chunks), wave q
// covers chunks q*8..q*8+7 of every slot (key index wave-uniform -> LDS
// broadcast), 4-way partials combined through s_red.
__global__ __launch_bounds__(256) void cw_scores(
    const float* __restrict__ mem,
    const float* __restrict__ keys,
    const float* __restrict__ ws,
    float* __restrict__ out)
{
  __shared__ float4 s_mem[64 * 32];   // 32 KB: slot-major, chunk xor-swizzled
  __shared__ float4 s_keys[kH * 32];  // 4 KB
  __shared__ float s_red[4 * 64 * 9]; // 9.2 KB: [wave][slot][8 dots + norm]
  __shared__ float s_kn[kH], s_adj[kH];

  const int t = threadIdx.x;
  const int b = blockIdx.x >> 8;
  const int m0 = (blockIdx.x & 255) << 6;

  // Stage keys (1024 floats = 256 float4, one per thread) + stats.
  s_keys[t] = ((const float4*)(keys + (size_t)b * kH * kW))[t];
  if (t < kH) {
    s_kn[t] = ws[b * kH + t];
    s_adj[t] = ws[kB * kH + b * kH + t];
  }

  // Stage 64 slots = 2048 float4, coalesced; phys chunk = c ^ (slot&7)
  // keeps 16-B alignment and balances banks for both write and read.
  const float4* g = (const float4*)(mem + ((size_t)b * kM + m0) * kW);
  #pragma unroll
  for (int r = 0; r < 8; ++r) {
    const int gi = r * 256 + t;
    const int s = gi >> 5, c = gi & 31;
    s_mem[s * 32 + (c ^ (s & 7))] = g[gi];
  }
  __syncthreads();

  // Wave q handles chunks q*8..q*8+7 of slot `lane`.
  const int q = t >> 6, lane = t & 63;
  float d[kH];
  float n = 0.f;
  #pragma unroll
  for (int h = 0; h < kH; ++h) d[h] = 0.f;

  #pragma unroll
  for (int j = 0; j < 8; ++j) {
    const int c = q * 8 + j;
    const float4 v = s_mem[lane * 32 + (c ^ (lane & 7))];
    n = fmaf(v.x, v.x, fmaf(v.y, v.y, fmaf(v.z, v.z, fmaf(v.w, v.w, n))));
    #pragma unroll
    for (int h = 0; h < kH; ++h) {
      const float4 kk = s_keys[h * 32 + c];  // wave-uniform -> broadcast
      d[h] = fmaf(v.x, kk.x, fmaf(v.y, kk.y, fmaf(v.z, kk.z, fmaf(v.w, kk.w, d[h]))));
    }
  }

  float* rp = s_red + (q * 64 + lane) * 9;
  #pragma unroll
  for (int h = 0; h < kH; ++h) rp[h] = d[h];
  rp[8] = n;
  __syncthreads();

  if (t < 64) {
    float f[9];
    #pragma unroll
    for (int k = 0; k < 9; ++k)
      f[k] = s_red[t * 9 + k] + s_red[(64 + t) * 9 + k] +
             s_red[(128 + t) * 9 + k] + s_red[(192 + t) * 9 + k];
    const float mn = sqrtf(f[8]);
    float* op = out + (size_t)b * kH * kM + m0 + t;
    #pragma unroll
    for (int h = 0; h < kH; ++h)
      op[h * kM] = s_adj[h] * f[h] / fmaf(mn, s_kn[h], kEps);  // coalesced per head
  }
}

// ---------------------------------------------------------------------------
// K2: in-place softmax over M per (b,h) row. Grid: kB*kH blocks x 256 threads.
// Whole row (16384 f32) lives in registers: 16 float4 per thread.
__global__ __launch_bounds__(256) void cw_softmax(float* __restrict__ out)
{
  __shared__ float red[16];

  const int tid = threadIdx.x;
  const int wave = tid >> 6, lane = tid & 63;
  float4* p4 = (float4*)(out + (size_t)blockIdx.x * kM);

  float4 vs[16];
  float lmax = -INFINITY;
  #pragma unroll
  for (int k = 0; k < 16; ++k) {
    vs[k] = p4[k * 256 + tid];
    lmax = fmaxf(lmax, fmaxf(fmaxf(vs[k].x, vs[k].y), fmaxf(vs[k].z, vs[k].w)));
  }
  #pragma unroll
  for (int off = 32; off > 0; off >>= 1) lmax = fmaxf(lmax, __shfl_xor(lmax, off));
  if (lane == 0) red[wave] = lmax;
  __syncthreads();
  const float bmax = fmaxf(fmaxf(red[0], red[1]), fmaxf(red[2], red[3]));

  float lsum = 0.f;
  #pragma unroll
  for (int k = 0; k < 16; ++k) {
    vs[k].x = __expf(vs[k].x - bmax);
    vs[k].y = __expf(vs[k].y - bmax);
    vs[k].z = __expf(vs[k].z - bmax);
    vs[k].w = __expf(vs[k].w - bmax);
    lsum += (vs[k].x + vs[k].y) + (vs[k].z + vs[k].w);
  }
  #pragma unroll
  for (int off = 32; off > 0; off >>= 1) lsum += __shfl_xor(lsum, off);
  if (lane == 0) red[8 + wave] = lsum;
  __syncthreads();
  const float inv = 1.f / ((red[8] + red[9]) + (red[10] + red[11]));

  #pragma unroll
  for (int k = 0; k < 16; ++k) {
    vs[k].x *= inv; vs[k].y *= inv; vs[k].z *= inv; vs[k].w *= inv;
    p4[k * 256 + tid] = vs[k];
  }
}

}  // namespace

extern "C" void kernel_launch(void* const* d_in, const int* in_sizes, int n_in,
                              void* d_out, int out_size, void* d_ws, size_t ws_size,
                              hipStream_t stream) {
  (void)in_sizes; (void)n_in; (void)ws_size; (void)out_size;
  const float* mem       = (const float*)d_in[0];
  const float* keys      = (const float*)d_in[1];
  const float* strengths = (const float*)d_in[2];
  float* out = (float*)d_out;
  float* wsf = (float*)d_ws;  // 1024 floats: [kn | adj]

  cw_stats<<<dim3(kB), dim3(256), 0, stream>>>(keys, strengths, wsf);
  cw_scores<<<dim3(kB * (kM / 64)), dim3(256), 0, stream>>>(mem, keys, wsf, out);
  cw_softmax<<<dim3(kB * kH), dim3(256), 0, stream>>>(out);
}